// Round 2
// baseline (516.822 us; speedup 1.0000x reference)
//
#include <hip/hip_runtime.h>
#include <hip/hip_bf16.h>

// Decoder: 2-layer LSTM (H=32) + MLP head (96), B=16384, 25 autoregressive steps.
// R1 NaN => inputs are NOT bf16-coded. This round: runtime dtype probe (uniform
// per-block) selects f32 vs bf16 decode for staging and output packing.
// Hot loop is f32 LDS GEMMs either way.

#define NTHR 256
#define ET   64      // batch elements per block
#define XS   68      // LDS row stride (floats): 16B-aligned, bank-friendly
#define PRED 25
#define BATCH 16384

typedef unsigned short u16;
typedef unsigned int   u32;

__device__ __forceinline__ float b2f(u16 u){ return __uint_as_float(((u32)u) << 16); }
__device__ __forceinline__ u16 f2b(float f){
  u32 i = __float_as_uint(f);
  i += 0x7FFFu + ((i >> 16) & 1u);
  return (u16)(i >> 16);
}
__device__ __forceinline__ float fast_rcp(float x){ return __builtin_amdgcn_rcpf(x); }
__device__ __forceinline__ float sigm(float x){ return fast_rcp(1.0f + __expf(-x)); }
__device__ __forceinline__ float tanh_(float x){ return 1.0f - 2.0f*fast_rcp(__expf(2.0f*x) + 1.0f); }

// dtype-agnostic element load: element i of a logical float tensor
__device__ __forceinline__ float ld(const void* p, int i, bool isf32){
  return isf32 ? ((const float*)p)[i] : b2f(((const u16*)p)[i]);
}

struct SM {
  float w0[128][128];  // [k][vg]  k<96: W_ih0, k>=96: W_hh0 ; vg = u*4+tt, gate g = tt*32+u
  float w1[64][128];   // [k][vg]  k<32: W_ih1 (x=h0),  k>=32: W_hh1 (h=h1)
  float wm[32][96];    // [k][o]   W_mlp[o][k]
  float xh[128][XS];   // [k][e]   rows 0..95: last/curr pose, 96..127: h0
  float hh[64][XS];    // [k][e]   rows 0..31: h0, 32..63: h1
};

extern "C" __global__ __launch_bounds__(NTHR, 1)
void decoder_kernel(const void* __restrict__ obs,   // [16][B][96]
                    const void* __restrict__ lat,   // [B][16]
                    const void* __restrict__ Wfc,   // [32][16]
                    const void* __restrict__ bfc,   // [32]
                    const void* __restrict__ Wih0,  // [128][96]
                    const void* __restrict__ Whh0,  // [128][32]
                    const void* __restrict__ bih0,  // [128]
                    const void* __restrict__ bhh0,  // [128]
                    const void* __restrict__ Wih1,  // [128][32]
                    const void* __restrict__ Whh1,  // [128][32]
                    const void* __restrict__ bih1,  // [128]
                    const void* __restrict__ bhh1,  // [128]
                    const void* __restrict__ Wmlp,  // [96][32]
                    const void* __restrict__ bmlp,  // [96]
                    void* __restrict__ out)         // [25][B][96]
{
  __shared__ SM sm;
  const int tid = threadIdx.x;
  const int ebase = blockIdx.x * ET;

  // ---- dtype probe: bf16 weights (scale 0.1) never have exponent >= 0x90;
  //      f32 words read as u16 pairs give ~112/512 such hits. Uniform result.
  int cnt = 0;
  {
    const u16* p = (const u16*)Wfc;
    for (int i = 0; i < 512; ++i){
      int e = (p[i] >> 7) & 0xFF;
      cnt += (e >= 0x90);
    }
  }
  const bool isf32 = (cnt > 0);

  // ---- stage weights into LDS (f32), gate-permuted columns ----
  for (int idx = tid; idx < 128*128; idx += NTHR){
    int k = idx >> 7, vg = idx & 127;
    int u = vg >> 2, tt = vg & 3, g = tt*32 + u;
    sm.w0[k][vg] = (k < 96) ? ld(Wih0, g*96 + k, isf32) : ld(Whh0, g*32 + (k-96), isf32);
  }
  for (int idx = tid; idx < 64*128; idx += NTHR){
    int k = idx >> 7, vg = idx & 127;
    int u = vg >> 2, tt = vg & 3, g = tt*32 + u;
    sm.w1[k][vg] = (k < 32) ? ld(Wih1, g*32 + k, isf32) : ld(Whh1, g*32 + (k-32), isf32);
  }
  for (int idx = tid; idx < 32*96; idx += NTHR){
    int k = idx / 96, o = idx - k*96;
    sm.wm[k][o] = ld(Wmlp, o*32 + k, isf32);
  }
  // ---- state init: last = obs_s[15], h0 = h1 = h_init, c = 0 ----
  for (int idx = tid; idx < 96*ET; idx += NTHR){
    int e = idx / 96, p = idx - e*96;
    sm.xh[p][e] = ld(obs, (15*BATCH + ebase + e)*96 + p, isf32);
  }
  for (int idx = tid; idx < 32*ET; idx += NTHR){
    int e = idx >> 5, u = idx & 31;
    float a = ld(bfc, u, isf32);
    const int lbase = (ebase + e)*16;
    #pragma unroll
    for (int j = 0; j < 16; ++j) a = fmaf(ld(Wfc, u*16 + j, isf32), ld(lat, lbase + j, isf32), a);
    sm.xh[96+u][e] = a;
    sm.hh[u][e] = a;
    sm.hh[32+u][e] = a;
  }

  // ---- per-thread tile mapping ----
  const int ug  = tid >> 4;         // 16 gate-groups: units {2ug, 2ug+1}
  const int e0  = (tid & 15) * 4;   // 4-elem tile
  const int vg0 = ug * 8;
  const int o0  = (tid >> 3) * 3;   // MLP: 3 outputs
  const int e0m = (tid & 7) * 8;    // MLP: 8-elem tile

  float bias0[8], bias1[8];
  #pragma unroll
  for (int i = 0; i < 8; ++i){
    int vg = vg0 + i; int u = vg >> 2, tt = vg & 3, g = tt*32 + u;
    bias0[i] = ld(bih0, g, isf32) + ld(bhh0, g, isf32);
    bias1[i] = ld(bih1, g, isf32) + ld(bhh1, g, isf32);
  }
  float biasm[3];
  #pragma unroll
  for (int i = 0; i < 3; ++i) biasm[i] = ld(bmlp, o0 + i, isf32);

  float c0s[2][4], c1s[2][4];
  #pragma unroll
  for (int du = 0; du < 2; ++du)
    #pragma unroll
    for (int j = 0; j < 4; ++j){ c0s[du][j] = 0.f; c1s[du][j] = 0.f; }

  __syncthreads();

  for (int t = 0; t < PRED; ++t){
    // ---- GEMM0: gates0 = [last;h0]^T @ w0  (K=128) ----
    float acc[8][4];
    #pragma unroll
    for (int i = 0; i < 8; ++i){
      float b = bias0[i];
      acc[i][0]=b; acc[i][1]=b; acc[i][2]=b; acc[i][3]=b;
    }
    #pragma unroll 4
    for (int k = 0; k < 128; ++k){
      const float4 xv = *(const float4*)&sm.xh[k][e0];
      const float4 wa = *(const float4*)&sm.w0[k][vg0];
      const float4 wb = *(const float4*)&sm.w0[k][vg0+4];
      const float xr[4] = {xv.x, xv.y, xv.z, xv.w};
      const float wr[8] = {wa.x, wa.y, wa.z, wa.w, wb.x, wb.y, wb.z, wb.w};
      #pragma unroll
      for (int i = 0; i < 8; ++i)
        #pragma unroll
        for (int j = 0; j < 4; ++j)
          acc[i][j] = fmaf(wr[i], xr[j], acc[i][j]);
    }
    __syncthreads();   // all xh reads done
    // ---- LSTM0 activation (register-local i,f,g,o) ----
    #pragma unroll
    for (int du = 0; du < 2; ++du){
      const int u = ug*2 + du;
      #pragma unroll
      for (int j = 0; j < 4; ++j){
        float ig = sigm(acc[du*4+0][j]);
        float fg = sigm(acc[du*4+1][j]);
        float gg = tanh_(acc[du*4+2][j]);
        float og = sigm(acc[du*4+3][j]);
        float cn = fmaf(fg, c0s[du][j], ig*gg);
        c0s[du][j] = cn;
        float h = og * tanh_(cn);
        sm.xh[96+u][e0+j] = h;
        sm.hh[u][e0+j] = h;
      }
    }
    __syncthreads();   // h0 visible
    // ---- GEMM1: gates1 = [h0;h1]^T @ w1  (K=64) ----
    #pragma unroll
    for (int i = 0; i < 8; ++i){
      float b = bias1[i];
      acc[i][0]=b; acc[i][1]=b; acc[i][2]=b; acc[i][3]=b;
    }
    #pragma unroll 4
    for (int k = 0; k < 64; ++k){
      const float4 xv = *(const float4*)&sm.hh[k][e0];
      const float4 wa = *(const float4*)&sm.w1[k][vg0];
      const float4 wb = *(const float4*)&sm.w1[k][vg0+4];
      const float xr[4] = {xv.x, xv.y, xv.z, xv.w};
      const float wr[8] = {wa.x, wa.y, wa.z, wa.w, wb.x, wb.y, wb.z, wb.w};
      #pragma unroll
      for (int i = 0; i < 8; ++i)
        #pragma unroll
        for (int j = 0; j < 4; ++j)
          acc[i][j] = fmaf(wr[i], xr[j], acc[i][j]);
    }
    __syncthreads();   // hh reads done
    // ---- LSTM1 activation ----
    #pragma unroll
    for (int du = 0; du < 2; ++du){
      const int u = ug*2 + du;
      #pragma unroll
      for (int j = 0; j < 4; ++j){
        float ig = sigm(acc[du*4+0][j]);
        float fg = sigm(acc[du*4+1][j]);
        float gg = tanh_(acc[du*4+2][j]);
        float og = sigm(acc[du*4+3][j]);
        float cn = fmaf(fg, c1s[du][j], ig*gg);
        c1s[du][j] = cn;
        float h = og * tanh_(cn);
        sm.hh[32+u][e0+j] = h;
      }
    }
    __syncthreads();   // h1 visible
    // ---- MLP: curr = h1^T @ wm + b  (K=32) ----
    float am[3][8];
    #pragma unroll
    for (int i = 0; i < 3; ++i){
      float b = biasm[i];
      #pragma unroll
      for (int j = 0; j < 8; ++j) am[i][j] = b;
    }
    #pragma unroll 4
    for (int k = 0; k < 32; ++k){
      const float4 ha = *(const float4*)&sm.hh[32+k][e0m];
      const float4 hb = *(const float4*)&sm.hh[32+k][e0m+4];
      const float hr[8] = {ha.x, ha.y, ha.z, ha.w, hb.x, hb.y, hb.z, hb.w};
      const float wr0 = sm.wm[k][o0];
      const float wr1 = sm.wm[k][o0+1];
      const float wr2 = sm.wm[k][o0+2];
      #pragma unroll
      for (int j = 0; j < 8; ++j){
        am[0][j] = fmaf(wr0, hr[j], am[0][j]);
        am[1][j] = fmaf(wr1, hr[j], am[1][j]);
        am[2][j] = fmaf(wr2, hr[j], am[2][j]);
      }
    }
    // write curr into xh rows 0..95 (next step's input); disjoint from hh reads
    #pragma unroll
    for (int i = 0; i < 3; ++i)
      #pragma unroll
      for (int j = 0; j < 8; ++j)
        sm.xh[o0+i][e0m+j] = am[i][j];
    __syncthreads();   // curr visible
    // ---- coalesced output: out[t][ebase..ebase+63][0..95] ----
    const size_t base = (size_t)t*BATCH*96 + (size_t)ebase*96;
    if (isf32){
      float* outf = (float*)out;
      for (int idx = tid; idx < ET*48; idx += NTHR){
        int e = idx / 48, op = idx - e*48;
        float2 v;
        v.x = sm.xh[op*2][e];
        v.y = sm.xh[op*2+1][e];
        *(float2*)&outf[base + e*96 + op*2] = v;
      }
    } else {
      u32* outw = (u32*)out + (base >> 1);
      for (int idx = tid; idx < ET*48; idx += NTHR){
        int e = idx / 48, op = idx - e*48;
        float v0 = sm.xh[op*2][e];
        float v1 = sm.xh[op*2+1][e];
        u32 pk = (u32)f2b(v0) | ((u32)f2b(v1) << 16);
        outw[e*48 + op] = pk;
      }
    }
    // no trailing barrier needed: next write to xh rows 0..95 is next step's MLP
    // (behind 4 barriers); rows 96..127 written after next step's GEMM0 barrier.
  }
}

extern "C" void kernel_launch(void* const* d_in, const int* in_sizes, int n_in,
                              void* d_out, int out_size, void* d_ws, size_t ws_size,
                              hipStream_t stream){
  // setup_inputs order; d_in[2] = pred_len (int scalar, ==25 compile-time here)
  decoder_kernel<<<dim3(BATCH/ET), dim3(NTHR), 0, stream>>>(
      d_in[0], d_in[1], d_in[3], d_in[4], d_in[5], d_in[6], d_in[7], d_in[8],
      d_in[9], d_in[10], d_in[11], d_in[12], d_in[13], d_in[14], d_out);
}